// Round 6
// baseline (122.739 us; speedup 1.0000x reference)
//
#include <hip/hip_runtime.h>
#include <hip/hip_bf16.h>

// Problem constants (from reference): b=2,h=8 -> BH=16; t=s=384; d=64.
#define BH 16
#define NT 384
#define NS 384
#define DD 64

static constexpr float TWO_LOG2E = 2.8853900817779268f; // 2*log2(e)
static constexpr float LOG2E     = 1.4426950408889634f;

// Static scratch: Ea = exp(2*qp), Eb = exp(2*kp). 2 x 1.5 MB, 16B aligned.
__device__ float4 g_Ea4[(size_t)BH * NT * DD / 4];
__device__ float4 g_Eb4[(size_t)BH * NS * DD / 4];

// ---------------------------------------------------------------------------
// K1: proj + exp. Block owns 32 rows of one tensor (q or k). x-tile staged in
// LDS; W row per lane in VGPRs; x read back as uniform LDS b128 broadcasts.
// ---------------------------------------------------------------------------
__global__ __launch_bounds__(256) void k1_proj(
    const float* __restrict__ q, const float* __restrict__ k,
    const float* __restrict__ Wq, const float* __restrict__ Wk)
{
    __shared__ float xt[32 * 64]; // 8KB
    const int bid    = blockIdx.x;       // [0, 384)
    const int tensor = bid / 192;        // 0=q, 1=k
    const int tile   = bid % 192;        // 32-row tiles over 6144 rows
    const int tid  = threadIdx.x;
    const int lane = tid & 63;
    const int w    = tid >> 6;

    const float* __restrict__ X = tensor ? k  : q;
    const float* __restrict__ W = tensor ? Wk : Wq;
    float* __restrict__ E = tensor ? (float*)g_Eb4 : (float*)g_Ea4;

    const size_t base = (size_t)tile * 32;

    {
        const float4* __restrict__ src =
            reinterpret_cast<const float4*>(X + base * 64);
        float4* dst = reinterpret_cast<float4*>(xt);
#pragma unroll
        for (int i = 0; i < 2; ++i) dst[tid + i * 256] = src[tid + i * 256];
    }

    float wr[64];
    {
        const float* wrow = W + lane * 64;
#pragma unroll
        for (int i = 0; i < 64; i += 4) {
            float4 v = *reinterpret_cast<const float4*>(wrow + i);
            wr[i] = v.x; wr[i + 1] = v.y; wr[i + 2] = v.z; wr[i + 3] = v.w;
        }
    }
    __syncthreads();

#pragma unroll
    for (int r8 = 0; r8 < 8; ++r8) {
        const int r = w * 8 + r8;
        float a0 = 0.f, a1 = 0.f, a2 = 0.f, a3 = 0.f;
#pragma unroll
        for (int d4 = 0; d4 < 16; ++d4) {
            const float4 xv = *reinterpret_cast<const float4*>(&xt[r * 64 + d4 * 4]);
            a0 = fmaf(xv.x, wr[d4 * 4 + 0], a0);
            a1 = fmaf(xv.y, wr[d4 * 4 + 1], a1);
            a2 = fmaf(xv.z, wr[d4 * 4 + 2], a2);
            a3 = fmaf(xv.w, wr[d4 * 4 + 3], a3);
        }
        const float dot = (a0 + a1) + (a2 + a3);
        E[(base + r) * 64 + lane] = __builtin_amdgcn_exp2f(TWO_LOG2E * dot);
    }
}

// ---------------------------------------------------------------------------
// K2 fused: scores + softmax + PV for one (bh, 8-t-row) tile per block.
// 4 waves/block; wave owns 2 t-rows; the 384-wide score row lives in 12 VGPRs
// (lane<->s, 6 chunks). Phase A: EbT staged [e][s] (pad 65) -> stride-1
// conflict-free b32 reads; Ea row + v_w are wave-uniform s_loads. Phase B:
// in-register softmax + single attn global write. Phase C: V chunk staged
// [s][d] (pad 68); lane = (d4 = (lane&15)*4, s-subgroup g = lane>>4); P
// broadcast via shfl; cross-group shfl_xor reduce; lanes<16 write out.
// Grid 768 (16 bh x 48 tiles), ~3 blocks/CU, 12 waves/CU.
// ---------------------------------------------------------------------------
__global__ __launch_bounds__(256) void k2_fused(
    const float* __restrict__ v_w, const float* __restrict__ V,
    float* __restrict__ out, float* __restrict__ attn)
{
    __shared__ float stage[64 * 68]; // 17.4KB, shared by EbT (64x65) and V (64x68)

    const int bid  = blockIdx.x;     // [0, 768)
    const int bh   = bid / 48;
    const int t0   = (bid % 48) * 8;
    const int tid  = threadIdx.x;
    const int lane = tid & 63;
    const int wv   = __builtin_amdgcn_readfirstlane(tid >> 6); // wave id 0..3
    const int r0   = t0 + 2 * wv;    // wave's first t-row (local in [0,384))

    // C0 = sum(v_w) — fully uniform, scalar ops
    float C0 = 0.f;
#pragma unroll
    for (int i = 0; i < 64; ++i) C0 += v_w[i];

    const float* __restrict__ ea0 = (const float*)g_Ea4 + ((size_t)bh * NT + r0) * 64;
    const float* __restrict__ ea1 = ea0 + 64;
    const float* __restrict__ Eb  = (const float*)g_Eb4 + (size_t)bh * NS * 64;

    float p0[6], p1[6]; // score rows, lane<->s within chunk

    // ---------------- Phase A: raw scores ----------------
    for (int sc = 0; sc < 6; ++sc) {
        __syncthreads();
        // stage EbT: [e][s] with row pitch 65
        {
            const float4* __restrict__ src =
                reinterpret_cast<const float4*>(Eb + (size_t)sc * 64 * 64);
#pragma unroll
            for (int i = 0; i < 4; ++i) {
                const int j = tid + i * 256;       // f4 index [0,1024)
                const float4 v = src[j];
                const int s  = j >> 4;
                const int e4 = j & 15;
                stage[(e4 * 4 + 0) * 65 + s] = v.x;
                stage[(e4 * 4 + 1) * 65 + s] = v.y;
                stage[(e4 * 4 + 2) * 65 + s] = v.z;
                stage[(e4 * 4 + 3) * 65 + s] = v.w;
            }
        }
        __syncthreads();

        float a00 = 0.f, a01 = 0.f, a02 = 0.f, a03 = 0.f;
        float a10 = 0.f, a11 = 0.f, a12 = 0.f, a13 = 0.f;
#pragma unroll
        for (int e = 0; e < 64; e += 4) {
            const float b0 = stage[(e + 0) * 65 + lane];
            const float b1 = stage[(e + 1) * 65 + lane];
            const float b2 = stage[(e + 2) * 65 + lane];
            const float b3 = stage[(e + 3) * 65 + lane];
            a00 = fmaf(v_w[e + 0], __builtin_amdgcn_rcpf(fmaf(ea0[e + 0], b0, 1.f)), a00);
            a01 = fmaf(v_w[e + 1], __builtin_amdgcn_rcpf(fmaf(ea0[e + 1], b1, 1.f)), a01);
            a02 = fmaf(v_w[e + 2], __builtin_amdgcn_rcpf(fmaf(ea0[e + 2], b2, 1.f)), a02);
            a03 = fmaf(v_w[e + 3], __builtin_amdgcn_rcpf(fmaf(ea0[e + 3], b3, 1.f)), a03);
            a10 = fmaf(v_w[e + 0], __builtin_amdgcn_rcpf(fmaf(ea1[e + 0], b0, 1.f)), a10);
            a11 = fmaf(v_w[e + 1], __builtin_amdgcn_rcpf(fmaf(ea1[e + 1], b1, 1.f)), a11);
            a12 = fmaf(v_w[e + 2], __builtin_amdgcn_rcpf(fmaf(ea1[e + 2], b2, 1.f)), a12);
            a13 = fmaf(v_w[e + 3], __builtin_amdgcn_rcpf(fmaf(ea1[e + 3], b3, 1.f)), a13);
        }
        p0[sc] = C0 - 2.f * ((a00 + a01) + (a02 + a03));
        p1[sc] = C0 - 2.f * ((a10 + a11) + (a12 + a13));
    }

    // ---------------- Phase B: in-register softmax + attn write ----------------
    {
        float m0 = fmaxf(fmaxf(fmaxf(p0[0], p0[1]), fmaxf(p0[2], p0[3])), fmaxf(p0[4], p0[5]));
        float m1 = fmaxf(fmaxf(fmaxf(p1[0], p1[1]), fmaxf(p1[2], p1[3])), fmaxf(p1[4], p1[5]));
#pragma unroll
        for (int o = 32; o > 0; o >>= 1) {
            m0 = fmaxf(m0, __shfl_xor(m0, o, 64));
            m1 = fmaxf(m1, __shfl_xor(m1, o, 64));
        }
        float s0 = 0.f, s1 = 0.f;
#pragma unroll
        for (int i = 0; i < 6; ++i) {
            p0[i] = __builtin_amdgcn_exp2f((p0[i] - m0) * LOG2E);
            p1[i] = __builtin_amdgcn_exp2f((p1[i] - m1) * LOG2E);
            s0 += p0[i];
            s1 += p1[i];
        }
#pragma unroll
        for (int o = 32; o > 0; o >>= 1) {
            s0 += __shfl_xor(s0, o, 64);
            s1 += __shfl_xor(s1, o, 64);
        }
        const float i0 = __builtin_amdgcn_rcpf(s0);
        const float i1 = __builtin_amdgcn_rcpf(s1);
        float* __restrict__ ar0 = attn + ((size_t)bh * NT + r0) * NS;
        float* __restrict__ ar1 = ar0 + NS;
#pragma unroll
        for (int i = 0; i < 6; ++i) {
            p0[i] *= i0;
            p1[i] *= i1;
            ar0[i * 64 + lane] = p0[i];
            ar1[i * 64 + lane] = p1[i];
        }
    }

    // ---------------- Phase C: PV ----------------
    const int g  = lane >> 4;        // s subgroup 0..3
    const int d4 = (lane & 15) * 4;  // this lane's d quad
    float4 O0 = {0.f, 0.f, 0.f, 0.f};
    float4 O1 = {0.f, 0.f, 0.f, 0.f};
    const float4* __restrict__ Vg =
        reinterpret_cast<const float4*>(V + (size_t)bh * NS * 64);

    for (int sc = 0; sc < 6; ++sc) {
        __syncthreads();
        // stage V chunk [64 s][64 d] with row pitch 68
        {
#pragma unroll
            for (int i = 0; i < 4; ++i) {
                const int j = tid + i * 256;       // f4 index [0,1024)
                const float4 v = Vg[(size_t)sc * 1024 + j];
                const int row = j >> 4;
                const int c4  = j & 15;
                *reinterpret_cast<float4*>(&stage[row * 68 + c4 * 4]) = v;
            }
        }
        __syncthreads();

#pragma unroll
        for (int s4 = 0; s4 < 16; ++s4) {
            const int sl = s4 * 4 + g; // s within chunk, per subgroup
            const float4 v4 = *reinterpret_cast<const float4*>(&stage[sl * 68 + d4]);
            const float q0 = __shfl(p0[sc], sl, 64);
            const float q1 = __shfl(p1[sc], sl, 64);
            O0.x = fmaf(q0, v4.x, O0.x); O0.y = fmaf(q0, v4.y, O0.y);
            O0.z = fmaf(q0, v4.z, O0.z); O0.w = fmaf(q0, v4.w, O0.w);
            O1.x = fmaf(q1, v4.x, O1.x); O1.y = fmaf(q1, v4.y, O1.y);
            O1.z = fmaf(q1, v4.z, O1.z); O1.w = fmaf(q1, v4.w, O1.w);
        }
    }

    // reduce partial O across the 4 s-subgroups (lane bits 4,5)
#pragma unroll
    for (int o = 16; o <= 32; o <<= 1) {
        O0.x += __shfl_xor(O0.x, o, 64); O0.y += __shfl_xor(O0.y, o, 64);
        O0.z += __shfl_xor(O0.z, o, 64); O0.w += __shfl_xor(O0.w, o, 64);
        O1.x += __shfl_xor(O1.x, o, 64); O1.y += __shfl_xor(O1.y, o, 64);
        O1.z += __shfl_xor(O1.z, o, 64); O1.w += __shfl_xor(O1.w, o, 64);
    }
    if (g == 0) {
        float* __restrict__ op = out + ((size_t)bh * NT + r0) * 64 + d4;
        *reinterpret_cast<float4*>(op)      = O0;
        *reinterpret_cast<float4*>(op + 64) = O1;
    }
}

extern "C" void kernel_launch(void* const* d_in, const int* in_sizes, int n_in,
                              void* d_out, int out_size, void* d_ws, size_t ws_size,
                              hipStream_t stream) {
    const float* q  = (const float*)d_in[0];
    const float* k  = (const float*)d_in[1];
    const float* v  = (const float*)d_in[2];
    const float* Wq = (const float*)d_in[3];
    const float* Wk = (const float*)d_in[4];
    const float* vw = (const float*)d_in[5];

    float* out  = (float*)d_out;              // (b,h,t,d) = 393216
    float* attn = out + (size_t)BH * NT * DD; // (b,h,t,s) = 2359296

    k1_proj <<<384, 256, 0, stream>>>(q, k, Wq, Wk);
    k2_fused<<<768, 256, 0, stream>>>(vw, v, out, attn);
}